// Round 4
// baseline (81.310 us; speedup 1.0000x reference)
//
#include <hip/hip_runtime.h>
#include <math.h>

#define NN  8192
#define DD  128
#define CLS 16
#define ALPHA 0.2f

// ---------------------------------------------------------------------------
// Kernel 1: per-row feature transform (unchanged, verified).
//   h[i] = (artanh(||x_i||)/||x_i||) * x_i @ W + b ; s=h.a_src ; dv=h.a_dst
// ---------------------------------------------------------------------------
__global__ __launch_bounds__(256) void hat_feat(
    const float* __restrict__ x, const float* __restrict__ W,
    const float* __restrict__ b, const float* __restrict__ a_src,
    const float* __restrict__ a_dst,
    float* __restrict__ h, float* __restrict__ s, float* __restrict__ dv)
{
    const int lane = threadIdx.x & 63;
    const int row  = (blockIdx.x << 2) + (threadIdx.x >> 6);

    const float* xr = x + (size_t)row * DD;
    float x0 = xr[lane];
    float x1 = xr[lane + 64];

    float nsq = x0 * x0 + x1 * x1;
    #pragma unroll
    for (int o = 32; o > 0; o >>= 1) nsq += __shfl_xor(nsq, o);

    float norm = fmaxf(sqrtf(nsq), 1e-15f);
    float t    = fminf(norm, 1.0f - 1e-7f);
    float art  = 0.5f * (log1pf(t) - log1pf(-t));
    float scl  = art / norm;
    x0 *= scl;
    x1 *= scl;

    float hc[CLS];
    #pragma unroll
    for (int c = 0; c < CLS; ++c)
        hc[c] = x0 * W[lane * CLS + c] + x1 * W[(lane + 64) * CLS + c];

    #pragma unroll
    for (int o = 32; o > 0; o >>= 1) {
        #pragma unroll
        for (int c = 0; c < CLS; ++c) hc[c] += __shfl_xor(hc[c], o);
    }

    float sv = 0.0f, dvv = 0.0f;
    #pragma unroll
    for (int c = 0; c < CLS; ++c) {
        hc[c] += b[c];
        sv  += hc[c] * a_src[c];
        dvv += hc[c] * a_dst[c];
    }

    if (lane == 0) {
        float* hr = h + (size_t)row * CLS;
        #pragma unroll
        for (int c = 0; c < CLS; ++c) hr[c] = hc[c];
        s[row]  = sv;
        dv[row] = dvv;
    }
}

// ---------------------------------------------------------------------------
// Kernel 2: two-phase ballot-scan attention. One wave per row.
// Phase 1: stream the adjacency row (coalesced uint4), fold to a per-lane
//          128-bit hit mask (2 x u64). No gathers here -> streaming loads
//          keep max MLP, no vmcnt drains from scattered loads.
// Phase 2: enumerate hits (1 ballot + shfl broadcast per active lane);
//          hit j is wave-uniform: broadcast dv[j]/h[j] line, uniform (m,l),
//          lane (c = lane&15) owns accumulator channel c.
// Encoding probe (byte-bool vs int32 0/1) folded in: 64 L2-hot diagonal
// bytes + ballot, identical in every wave (deterministic, wave-uniform).
// ---------------------------------------------------------------------------
__global__ __launch_bounds__(256) void hat_attn(
    const float* __restrict__ h, const float* __restrict__ s,
    const float* __restrict__ dv, const unsigned char* __restrict__ adj,
    float* __restrict__ out)
{
    const int lane = threadIdx.x & 63;
    const int row  = (blockIdx.x << 2) + (threadIdx.x >> 6);
    const int cc   = lane & 15;

    // ---- inline encoding probe (wave-uniform result) ----
    // byte-bool: adj[i*(NN+1)]!=0 for all i (self loops).
    // int32:     byte offset i*8193, i%4!=0 is an upper byte of 0/1 -> 0.
    {
    }
    const int pi = lane + 1;
    const int pok = ((pi & 3) != 0) && (adj[(size_t)pi * (NN + 1)] != 0);
    const bool bytemode = __popcll(__ballot(pok)) > 24;

    // ---- phase 1: stream row -> per-lane 128-bit hit mask ----
    unsigned long long m0 = 0ull, m1 = 0ull;
    if (bytemode) {
        // lane covers cols it*1024 + lane*16 + p (p=0..15); bit b = it*16+p
        const uint4* arow = reinterpret_cast<const uint4*>(adj + (size_t)row * NN);
        #pragma unroll
        for (int it = 0; it < 8; ++it) {
            const uint4 a = arow[(it << 6) | lane];
            unsigned n0 = ((a.x & 0x01010101u) * 0x01020408u) >> 24;
            unsigned n1 = ((a.y & 0x01010101u) * 0x01020408u) >> 24;
            unsigned n2 = ((a.z & 0x01010101u) * 0x01020408u) >> 24;
            unsigned n3 = ((a.w & 0x01010101u) * 0x01020408u) >> 24;
            unsigned long long bits = (unsigned long long)(
                (n0 & 0xF) | ((n1 & 0xF) << 4) | ((n2 & 0xF) << 8) | ((n3 & 0xF) << 12));
            if (it < 4) m0 |= bits << (it << 4);
            else        m1 |= bits << ((it - 4) << 4);
        }
    } else {
        // lane covers cols it*256 + lane*4 + k (k=0..3); bit b = it*4+k
        const uint4* arow = reinterpret_cast<const uint4*>(
            reinterpret_cast<const unsigned int*>(adj) + (size_t)row * NN);
        #pragma unroll
        for (int it = 0; it < 32; ++it) {
            const uint4 a = arow[(it << 6) | lane];
            unsigned long long bits =
                (unsigned long long)((a.x != 0u) | ((a.y != 0u) << 1) |
                                     ((a.z != 0u) << 2) | ((a.w != 0u) << 3));
            if (it < 16) m0 |= bits << (it << 2);
            else         m1 |= bits << ((it - 16) << 2);
        }
    }

    // ---- phase 2: wave-uniform hit processing ----
    const float si = s[row];
    float m = -3.0e38f, l = 0.0f, acc = 0.0f;

    auto hit = [&](int j) {
        float e = si + dv[j];
        e = (e > 0.0f) ? e : ALPHA * e;               // LeakyReLU
        float hv = h[(size_t)j * CLS + cc];           // 64B broadcast line
        if (e <= m) {                                  // common path: 1 exp
            float w = __expf(e - m);
            l += w;
            acc = fmaf(w, hv, acc);
        } else {                                       // new max: rescale
            float sc = __expf(m - e);                  // exp(-inf)=0 on 1st
            l   = fmaf(l, sc, 1.0f);                   // w = exp(0) = 1
            acc = fmaf(acc, sc, hv);
            m = e;
        }
    };

    auto decode = [&](int t, int b) -> int {
        return bytemode ? (((b >> 4) << 10) | (t << 4) | (b & 15))
                        : (((b >> 2) << 8)  | (t << 2) | (b & 3));
    };

    unsigned long long act = __ballot((m0 | m1) != 0ull);
    while (act) {
        const int t = __builtin_ctzll(act);
        act &= act - 1;
        unsigned long long mm0 = __shfl(m0, t);
        unsigned long long mm1 = __shfl(m1, t);
        while (mm0) {
            const int b = __builtin_ctzll(mm0);
            mm0 &= mm0 - 1;
            hit(decode(t, b));
        }
        while (mm1) {
            const int b = __builtin_ctzll(mm1);
            mm1 &= mm1 - 1;
            hit(decode(t, b + 64));
        }
    }

    // ---- epilogue: (m,l) uniform; acc channel cc lives in this lane ----
    float* orow = out + (size_t)row * CLS;
    if (l > 0.0f) {
        float u = acc / l;
        u = (u > 0.0f) ? u : expm1f(u);               // elu
        float nsq = u * u;                            // 16-wide group reduce
        #pragma unroll
        for (int o = 8; o > 0; o >>= 1) nsq += __shfl_xor(nsq, o);
        float norm = fmaxf(sqrtf(nsq), 1e-15f);
        float th   = tanhf(norm);
        float sc2  = th / norm;                        // expmap0 scale
        const float maxnorm = 1.0f - 1e-5f;            // proj (c=1)
        float sc3  = (th > maxnorm) ? (maxnorm / th) : 1.0f;
        if (lane < CLS) orow[lane] = u * sc2 * sc3;   // coalesced 64B store
    } else {
        if (lane < CLS) orow[lane] = 0.0f;
    }
}

// ---------------------------------------------------------------------------
extern "C" void kernel_launch(void* const* d_in, const int* in_sizes, int n_in,
                              void* d_out, int out_size, void* d_ws, size_t ws_size,
                              hipStream_t stream) {
    const float*         x     = (const float*)d_in[0];
    const unsigned char* adj   = (const unsigned char*)d_in[1];
    const float*         W     = (const float*)d_in[2];
    const float*         b     = (const float*)d_in[3];
    const float*         a_src = (const float*)d_in[4];
    const float*         a_dst = (const float*)d_in[5];
    float*               out   = (float*)d_out;

    float* h  = (float*)d_ws;                 // [NN, CLS]
    float* s  = h + (size_t)NN * CLS;         // [NN]
    float* dv = s + NN;                       // [NN]

    hat_feat<<<NN / 4, 256, 0, stream>>>(x, W, b, a_src, a_dst, h, s, dv);
    hat_attn<<<NN / 4, 256, 0, stream>>>(h, s, dv, adj, out);
}

// Round 5
// 72.204 us; speedup vs baseline: 1.1261x; 1.1261x over previous
//
#include <hip/hip_runtime.h>
#include <math.h>

#define NN   8192
#define DD   128
#define CLS  16
#define ALPHA 0.2f
#define MAXD 1024          // neighbor-list capacity per row (deg ~32±6; 1024 is >>150 sigma)

// ---------------------------------------------------------------------------
// Probe: decide adjacency encoding (byte-bool vs int32 0/1). One tiny block.
//   byte-bool: adj[i*(NN+1)] != 0 for all i (self loops).
//   int32:     byte offset i*8193 with i%4!=0 is an upper byte of 0/1 -> 0.
// ---------------------------------------------------------------------------
__global__ void adj_probe(const unsigned char* __restrict__ adj, int* flag)
{
    const int lane = threadIdx.x & 63;
    const int i = lane + 1;                           // rows 1..64
    const int ok = ((i & 3) != 0) && (adj[(size_t)i * (NN + 1)] != 0);
    unsigned long long b = __ballot(ok);
    if (threadIdx.x == 0) *flag = (__popcll(b) > 24) ? 1 : 0;
}

// ---------------------------------------------------------------------------
// Kernel 1: per-row feature transform (verified rounds 2-4).
//   h[i] = (artanh(||x_i||)/||x_i||) * x_i @ W + b ; s=h.a_src ; dv=h.a_dst
// ---------------------------------------------------------------------------
__global__ __launch_bounds__(256) void hat_feat(
    const float* __restrict__ x, const float* __restrict__ W,
    const float* __restrict__ b, const float* __restrict__ a_src,
    const float* __restrict__ a_dst,
    float* __restrict__ h, float* __restrict__ s, float* __restrict__ dv)
{
    const int lane = threadIdx.x & 63;
    const int row  = (blockIdx.x << 2) + (threadIdx.x >> 6);

    const float* xr = x + (size_t)row * DD;
    float x0 = xr[lane];
    float x1 = xr[lane + 64];

    float nsq = x0 * x0 + x1 * x1;
    #pragma unroll
    for (int o = 32; o > 0; o >>= 1) nsq += __shfl_xor(nsq, o);

    float norm = fmaxf(sqrtf(nsq), 1e-15f);
    float t    = fminf(norm, 1.0f - 1e-7f);
    float art  = 0.5f * (log1pf(t) - log1pf(-t));
    float scl  = art / norm;
    x0 *= scl;
    x1 *= scl;

    float hc[CLS];
    #pragma unroll
    for (int c = 0; c < CLS; ++c)
        hc[c] = x0 * W[lane * CLS + c] + x1 * W[(lane + 64) * CLS + c];

    #pragma unroll
    for (int o = 32; o > 0; o >>= 1) {
        #pragma unroll
        for (int c = 0; c < CLS; ++c) hc[c] += __shfl_xor(hc[c], o);
    }

    float sv = 0.0f, dvv = 0.0f;
    #pragma unroll
    for (int c = 0; c < CLS; ++c) {
        hc[c] += b[c];
        sv  += hc[c] * a_src[c];
        dvv += hc[c] * a_dst[c];
    }

    if (lane == 0) {
        float* hr = h + (size_t)row * CLS;
        #pragma unroll
        for (int c = 0; c < CLS; ++c) hr[c] = hc[c];
        s[row]  = sv;
        dv[row] = dvv;
    }
}

// ---------------------------------------------------------------------------
// Kernel 2a: pure-streaming adjacency scan -> compact neighbor lists.
// One wave per row. Nothing between the coalesced uint4 loads but a few
// VALU fold ops; hit indices compacted deterministically via 64-lane
// prefix sum, written to nbr[row*MAXD .. ].
// ---------------------------------------------------------------------------
__global__ __launch_bounds__(256) void hat_scan(
    const unsigned char* __restrict__ adj, const int* __restrict__ flag,
    int* __restrict__ nbr, int* __restrict__ cnt)
{
    const int lane = threadIdx.x & 63;
    const int row  = (blockIdx.x << 2) + (threadIdx.x >> 6);
    const bool bytemode = (*flag != 0);               // wave-uniform scalar

    unsigned long long m0 = 0ull, m1 = 0ull;          // per-lane hit bits
    if (bytemode) {
        // lane covers cols it*1024 + lane*16 + p ; bit b = it*16 + p
        const uint4* arow = reinterpret_cast<const uint4*>(adj + (size_t)row * NN);
        #pragma unroll
        for (int it = 0; it < 8; ++it) {
            const uint4 a = arow[(it << 6) | lane];
            unsigned n0 = ((a.x & 0x01010101u) * 0x01020408u) >> 24;
            unsigned n1 = ((a.y & 0x01010101u) * 0x01020408u) >> 24;
            unsigned n2 = ((a.z & 0x01010101u) * 0x01020408u) >> 24;
            unsigned n3 = ((a.w & 0x01010101u) * 0x01020408u) >> 24;
            unsigned long long bits = (unsigned long long)(
                (n0 & 0xF) | ((n1 & 0xF) << 4) | ((n2 & 0xF) << 8) | ((n3 & 0xF) << 12));
            if (it < 4) m0 |= bits << (it << 4);
            else        m1 |= bits << ((it - 4) << 4);
        }
    } else {
        // lane covers cols it*256 + lane*4 + k ; bit b = it*4 + k
        const uint4* arow = reinterpret_cast<const uint4*>(
            reinterpret_cast<const unsigned int*>(adj) + (size_t)row * NN);
        #pragma unroll
        for (int it = 0; it < 32; ++it) {
            const uint4 a = arow[(it << 6) | lane];
            unsigned long long bits =
                (unsigned long long)((a.x != 0u) | ((a.y != 0u) << 1) |
                                     ((a.z != 0u) << 2) | ((a.w != 0u) << 3));
            if (it < 16) m0 |= bits << (it << 2);
            else         m1 |= bits << ((it - 16) << 2);
        }
    }

    // deterministic compaction: exclusive prefix of per-lane popcounts
    const int c = __popcll(m0) + __popcll(m1);
    int off = c;
    #pragma unroll
    for (int o = 1; o < 64; o <<= 1) {
        int v = __shfl_up(off, o);
        if (lane >= o) off += v;
    }
    const int total = __shfl(off, 63);
    off -= c;                                          // exclusive offset

    int* rbase = nbr + (size_t)row * MAXD;
    while (m0) {
        const int b = __builtin_ctzll(m0);
        m0 &= m0 - 1;
        const int j = bytemode ? (((b >> 4) << 10) | (lane << 4) | (b & 15))
                               : (((b >> 2) << 8)  | (lane << 2) | (b & 3));
        if (off < MAXD) rbase[off] = j;
        ++off;
    }
    while (m1) {
        const int b0 = __builtin_ctzll(m1);
        m1 &= m1 - 1;
        const int b = b0 + 64;
        const int j = bytemode ? (((b >> 4) << 10) | (lane << 4) | (b & 15))
                               : (((b >> 2) << 8)  | (lane << 2) | (b & 3));
        if (off < MAXD) rbase[off] = j;
        ++off;
    }
    if (lane == 0) cnt[row] = (total < MAXD) ? total : MAXD;
}

// ---------------------------------------------------------------------------
// Kernel 2b: softmax-aggregate over compact lists (all data L2-hot).
// One wave per row. Pass 1: lane-parallel max. Pass 2: 4-hit-parallel
// channel-split accumulate (group g=lane>>4 takes hit base+g; lane owns
// channel cc=lane&15) -> pipelined independent iterations.
// ---------------------------------------------------------------------------
__global__ __launch_bounds__(256) void hat_agg(
    const float* __restrict__ h, const float* __restrict__ s,
    const float* __restrict__ dv, const int* __restrict__ nbr,
    const int* __restrict__ cnt, float* __restrict__ out)
{
    const int lane = threadIdx.x & 63;
    const int row  = (blockIdx.x << 2) + (threadIdx.x >> 6);
    const int cc   = lane & 15;
    const int g    = lane >> 4;

    const int n = cnt[row];
    const int* rbase = nbr + (size_t)row * MAXD;
    const float si = s[row];

    // pass 1: global max of leaky_relu(si + dv[j])
    float mx = -3.0e38f;
    for (int i = lane; i < n; i += 64) {
        float e = si + dv[rbase[i]];
        e = (e > 0.0f) ? e : ALPHA * e;
        mx = fmaxf(mx, e);
    }
    #pragma unroll
    for (int o = 32; o > 0; o >>= 1) mx = fmaxf(mx, __shfl_xor(mx, o));

    // pass 2: l = sum w ; acc[cc] = sum w*h[j][cc]  (4 hits in flight)
    float l = 0.0f, acc = 0.0f;
    #pragma unroll 2
    for (int base = 0; base < n; base += 4) {
        const int idx = base + g;
        if (idx < n) {
            const int j = rbase[idx];
            float e = si + dv[j];
            e = (e > 0.0f) ? e : ALPHA * e;
            const float w = __expf(e - mx);
            l += w;
            acc = fmaf(w, h[(size_t)j * CLS + cc], acc);
        }
    }
    l   += __shfl_xor(l, 16);   l   += __shfl_xor(l, 32);
    acc += __shfl_xor(acc, 16); acc += __shfl_xor(acc, 32);

    // epilogue (verified): elu -> expmap0 -> proj
    float* orow = out + (size_t)row * CLS;
    if (l > 0.0f) {
        float u = acc / l;
        u = (u > 0.0f) ? u : expm1f(u);
        float nsq = u * u;
        #pragma unroll
        for (int o = 8; o > 0; o >>= 1) nsq += __shfl_xor(nsq, o);
        float norm = fmaxf(sqrtf(nsq), 1e-15f);
        float th   = tanhf(norm);
        float sc2  = th / norm;
        const float maxnorm = 1.0f - 1e-5f;
        float sc3  = (th > maxnorm) ? (maxnorm / th) : 1.0f;
        if (lane < CLS) orow[lane] = u * sc2 * sc3;
    } else {
        if (lane < CLS) orow[lane] = 0.0f;
    }
}

// ---------------------------------------------------------------------------
extern "C" void kernel_launch(void* const* d_in, const int* in_sizes, int n_in,
                              void* d_out, int out_size, void* d_ws, size_t ws_size,
                              hipStream_t stream) {
    const float*         x     = (const float*)d_in[0];
    const unsigned char* adj   = (const unsigned char*)d_in[1];
    const float*         W     = (const float*)d_in[2];
    const float*         b     = (const float*)d_in[3];
    const float*         a_src = (const float*)d_in[4];
    const float*         a_dst = (const float*)d_in[5];
    float*               out   = (float*)d_out;

    float* h    = (float*)d_ws;                    // [NN, CLS]
    float* s    = h + (size_t)NN * CLS;            // [NN]
    float* dv   = s + NN;                          // [NN]
    int*   flag = (int*)(dv + NN);                 // [1]
    int*   cnt  = flag + 1;                        // [NN]
    int*   nbr  = cnt + NN;                        // [NN, MAXD]

    adj_probe<<<1, 64, 0, stream>>>(adj, flag);
    hat_feat<<<NN / 4, 256, 0, stream>>>(x, W, b, a_src, a_dst, h, s, dv);
    hat_scan<<<NN / 4, 256, 0, stream>>>(adj, flag, nbr, cnt);
    hat_agg <<<NN / 4, 256, 0, stream>>>(h, s, dv, nbr, cnt, out);
}

// Round 6
// 69.166 us; speedup vs baseline: 1.1756x; 1.0439x over previous
//
#include <hip/hip_runtime.h>
#include <math.h>

#define NN   8192
#define DD   128
#define CLS  16
#define ALPHA 0.2f
#define SEGCAP 256      // neighbor capacity per quarter-row (expected ~8)

// ---------------------------------------------------------------------------
// Kernel 1: per-row feature transform (verified r2-r5) + embedded encoding
// probe (block 0, wave 0): byte-bool vs int32 0/1 adjacency.
//   h[i] = (artanh(||x_i||)/||x_i||) * x_i @ W + b ; s=h.a_src ; dv=h.a_dst
// ---------------------------------------------------------------------------
__global__ __launch_bounds__(256) void hat_feat(
    const float* __restrict__ x, const float* __restrict__ W,
    const float* __restrict__ b, const float* __restrict__ a_src,
    const float* __restrict__ a_dst, const unsigned char* __restrict__ adj,
    float* __restrict__ h, float* __restrict__ s, float* __restrict__ dv,
    int* __restrict__ flag)
{
    const int lane = threadIdx.x & 63;
    const int row  = (blockIdx.x << 2) + (threadIdx.x >> 6);

    // ---- encoding probe: block 0, wave 0 (threads 0..63) ----
    // byte-bool: adj[i*(NN+1)] != 0 for all i (self loops).
    // int32:     byte offset i*8193 with i%4!=0 is an upper byte of 0/1 -> 0.
    if (blockIdx.x == 0 && threadIdx.x < 64) {
        const int i = threadIdx.x + 1;
        const int ok = ((i & 3) != 0) && (adj[(size_t)i * (NN + 1)] != 0);
        unsigned long long bb = __ballot(ok);
        if (threadIdx.x == 0) *flag = (__popcll(bb) > 24) ? 1 : 0;
    }

    const float* xr = x + (size_t)row * DD;
    float x0 = xr[lane];
    float x1 = xr[lane + 64];

    float nsq = x0 * x0 + x1 * x1;
    #pragma unroll
    for (int o = 32; o > 0; o >>= 1) nsq += __shfl_xor(nsq, o);

    float norm = fmaxf(sqrtf(nsq), 1e-15f);
    float t    = fminf(norm, 1.0f - 1e-7f);
    float art  = 0.5f * (log1pf(t) - log1pf(-t));
    float scl  = art / norm;
    x0 *= scl;
    x1 *= scl;

    float hc[CLS];
    #pragma unroll
    for (int c = 0; c < CLS; ++c)
        hc[c] = x0 * W[lane * CLS + c] + x1 * W[(lane + 64) * CLS + c];

    #pragma unroll
    for (int o = 32; o > 0; o >>= 1) {
        #pragma unroll
        for (int c = 0; c < CLS; ++c) hc[c] += __shfl_xor(hc[c], o);
    }

    float sv = 0.0f, dvv = 0.0f;
    #pragma unroll
    for (int c = 0; c < CLS; ++c) {
        hc[c] += b[c];
        sv  += hc[c] * a_src[c];
        dvv += hc[c] * a_dst[c];
    }

    if (lane == 0) {
        float* hr = h + (size_t)row * CLS;
        #pragma unroll
        for (int c = 0; c < CLS; ++c) hr[c] = hc[c];
        s[row]  = sv;
        dv[row] = dvv;
    }
}

// ---------------------------------------------------------------------------
// Kernel 2: streaming adjacency scan, 4 waves per row (quarter-rows).
// Each wave: 8 coalesced uint4 loads (int mode) or 2 (byte mode), ~5 VALU
// fold ops per load into a single u32 hit-mask per lane. Deterministic
// per-quarter compaction into nbr[(row*4+q)*SEGCAP ..].
// ---------------------------------------------------------------------------
__global__ __launch_bounds__(256) void hat_scan(
    const unsigned char* __restrict__ adj, const int* __restrict__ flag,
    int* __restrict__ nbr, int* __restrict__ cnt4)
{
    const int lane = threadIdx.x & 63;
    const int q    = threadIdx.x >> 6;        // quarter 0..3
    const int row  = blockIdx.x;
    const bool bytemode = (*flag != 0);       // wave-uniform scalar

    unsigned mask = 0u;                       // 32 hit bits per lane
    if (bytemode) {
        // quarter = 2048 bytes; lane covers bytes q*2048 + it*1024 + lane*16 + p
        const uint4* abase = reinterpret_cast<const uint4*>(
            adj + (size_t)row * NN + q * 2048);
        #pragma unroll
        for (int it = 0; it < 2; ++it) {
            const uint4 a = abase[(it << 6) | lane];
            unsigned n0 = ((a.x & 0x01010101u) * 0x01020408u) >> 24;
            unsigned n1 = ((a.y & 0x01010101u) * 0x01020408u) >> 24;
            unsigned n2 = ((a.z & 0x01010101u) * 0x01020408u) >> 24;
            unsigned n3 = ((a.w & 0x01010101u) * 0x01020408u) >> 24;
            unsigned bits = (n0 & 0xF) | ((n1 & 0xF) << 4)
                          | ((n2 & 0xF) << 8) | ((n3 & 0xF) << 12);
            mask |= bits << (it << 4);
        }
    } else {
        // quarter = 2048 dwords; lane covers dwords q*2048 + it*256 + lane*4 + k
        const uint4* abase = reinterpret_cast<const uint4*>(
            reinterpret_cast<const unsigned int*>(adj) + (size_t)row * NN + q * 2048);
        #pragma unroll
        for (int it = 0; it < 8; ++it) {
            const uint4 a = abase[(it << 6) | lane];
            unsigned bits = (unsigned)(a.x != 0u)        | ((unsigned)(a.y != 0u) << 1)
                          | ((unsigned)(a.z != 0u) << 2) | ((unsigned)(a.w != 0u) << 3);
            mask |= bits << (it << 2);
        }
    }

    // deterministic compaction within the wave (quarter segment)
    const int c = __popc(mask);
    int off = c;
    #pragma unroll
    for (int o = 1; o < 64; o <<= 1) {
        int v = __shfl_up(off, o);
        if (lane >= o) off += v;
    }
    const int total = __shfl(off, 63);
    off -= c;                                  // exclusive offset

    int* sb = nbr + ((size_t)row * 4 + q) * SEGCAP;
    while (mask) {
        const int b = __builtin_ctz(mask);
        mask &= mask - 1;
        const int j = bytemode
            ? (q * 2048 + ((b >> 4) << 10) + (lane << 4) + (b & 15))
            : (q * 2048 + ((b >> 2) << 8)  + (lane << 2) + (b & 3));
        if (off < SEGCAP) sb[off] = j;
        ++off;
    }
    if (lane == 0) cnt4[row * 4 + q] = (total < SEGCAP) ? total : SEGCAP;
}

// ---------------------------------------------------------------------------
// Kernel 3: softmax-aggregate over the 4 compact segments per row (L2-hot).
// One wave per row; pass 1 lane-parallel max; pass 2 4-hit-parallel
// channel-split accumulate (group g takes hit base+g, lane owns channel
// cc=lane&15); verified epilogue.
// ---------------------------------------------------------------------------
__global__ __launch_bounds__(256) void hat_agg(
    const float* __restrict__ h, const float* __restrict__ s,
    const float* __restrict__ dv, const int* __restrict__ nbr,
    const int* __restrict__ cnt4, float* __restrict__ out)
{
    const int lane = threadIdx.x & 63;
    const int row  = (blockIdx.x << 2) + (threadIdx.x >> 6);
    const int cc   = lane & 15;
    const int g    = lane >> 4;

    const float si = s[row];
    const int4 nq = *reinterpret_cast<const int4*>(cnt4 + row * 4);
    const int* rbase = nbr + (size_t)row * 4 * SEGCAP;

    // pass 1: global max of leaky_relu(si + dv[j])
    float mx = -3.0e38f;
    #pragma unroll
    for (int q = 0; q < 4; ++q) {
        const int n = (&nq.x)[q];
        const int* sb = rbase + q * SEGCAP;
        for (int i = lane; i < n; i += 64) {
            float e = si + dv[sb[i]];
            e = (e > 0.0f) ? e : ALPHA * e;
            mx = fmaxf(mx, e);
        }
    }
    #pragma unroll
    for (int o = 32; o > 0; o >>= 1) mx = fmaxf(mx, __shfl_xor(mx, o));

    // pass 2: l = sum w ; acc = sum w*h[j][cc]  (4 hits in flight)
    float l = 0.0f, acc = 0.0f;
    #pragma unroll
    for (int q = 0; q < 4; ++q) {
        const int n = (&nq.x)[q];
        const int* sb = rbase + q * SEGCAP;
        for (int base = 0; base < n; base += 4) {
            const int idx = base + g;
            if (idx < n) {
                const int j = sb[idx];
                float e = si + dv[j];
                e = (e > 0.0f) ? e : ALPHA * e;
                const float w = __expf(e - mx);
                l += w;
                acc = fmaf(w, h[(size_t)j * CLS + cc], acc);
            }
        }
    }
    l   += __shfl_xor(l, 16);   l   += __shfl_xor(l, 32);
    acc += __shfl_xor(acc, 16); acc += __shfl_xor(acc, 32);

    // epilogue (verified): elu -> expmap0 -> proj
    float* orow = out + (size_t)row * CLS;
    if (l > 0.0f) {
        float u = acc / l;
        u = (u > 0.0f) ? u : expm1f(u);
        float nsq = u * u;
        #pragma unroll
        for (int o = 8; o > 0; o >>= 1) nsq += __shfl_xor(nsq, o);
        float norm = fmaxf(sqrtf(nsq), 1e-15f);
        float th   = tanhf(norm);
        float sc2  = th / norm;
        const float maxnorm = 1.0f - 1e-5f;
        float sc3  = (th > maxnorm) ? (maxnorm / th) : 1.0f;
        if (lane < CLS) orow[lane] = u * sc2 * sc3;
    } else {
        if (lane < CLS) orow[lane] = 0.0f;
    }
}

// ---------------------------------------------------------------------------
extern "C" void kernel_launch(void* const* d_in, const int* in_sizes, int n_in,
                              void* d_out, int out_size, void* d_ws, size_t ws_size,
                              hipStream_t stream) {
    const float*         x     = (const float*)d_in[0];
    const unsigned char* adj   = (const unsigned char*)d_in[1];
    const float*         W     = (const float*)d_in[2];
    const float*         b     = (const float*)d_in[3];
    const float*         a_src = (const float*)d_in[4];
    const float*         a_dst = (const float*)d_in[5];
    float*               out   = (float*)d_out;

    float* h    = (float*)d_ws;                    // [NN, CLS]
    float* s    = h + (size_t)NN * CLS;            // [NN]
    float* dv   = s + NN;                          // [NN]
    int*   flag = (int*)(dv + NN);                 // [1]
    int*   cnt4 = flag + 1;                        // [NN*4]
    int*   nbr  = cnt4 + (size_t)NN * 4;           // [NN*4, SEGCAP]

    hat_feat<<<NN / 4, 256, 0, stream>>>(x, W, b, a_src, a_dst, adj, h, s, dv, flag);
    hat_scan<<<NN,     256, 0, stream>>>(adj, flag, nbr, cnt4);
    hat_agg <<<NN / 4, 256, 0, stream>>>(h, s, dv, nbr, cnt4, out);
}